// Round 5
// baseline (371.633 us; speedup 1.0000x reference)
//
#include <hip/hip_runtime.h>
#include <hip/hip_bf16.h>

// MLA prefill: B=4 S=1024 H=32 NOPE=128 ROPE=64 VDIM=128 Q_LORA=1536 KV_LORA=512
// v5: GEMMs -> 8-phase-class schedule: 256x128 tile, BK=64, 8 waves (4Mx2N),
// 3-buffer LDS rotation (144 KiB), counted vmcnt(6) once per K-tile (never 0
// in steady state), raw s_barrier + lgkmcnt(0) + setprio around 16-MFMA
// clusters, T2 XOR slot-swizzle both-sides. Attention/kpe/converts unchanged.

typedef __attribute__((ext_vector_type(8))) short s8v;
typedef __attribute__((ext_vector_type(4))) short s4v;
typedef __attribute__((ext_vector_type(4))) float f4v;

#define B_ 4
#define S_ 1024
#define H_ 32
#define SCALE_ 0.07216878364870322992f  // 1/sqrt(192)

__device__ __forceinline__ short f2bf(float f) {
  unsigned u = __builtin_bit_cast(unsigned, f);
  unsigned r = (u + 0x7FFFu + ((u >> 16) & 1u)) >> 16;
  return (short)(unsigned short)r;
}

// async global->LDS, 16B per lane; LDS dest = wave-uniform base + lane*16
__device__ __forceinline__ void gll16(const void* g, void* l) {
  __builtin_amdgcn_global_load_lds((const __attribute__((address_space(1))) void*)g,
                                   (__attribute__((address_space(3))) void*)l, 16, 0, 0);
}

// ---------------- fp32 -> bf16 convert (vectorized x4) ----------------
__global__ __launch_bounds__(256) void convert_f32_bf16(const float* __restrict__ src,
                                                        short* __restrict__ dst, int n4) {
  int i = blockIdx.x * 256 + threadIdx.x;
  if (i >= n4) return;
  float4 v = reinterpret_cast<const float4*>(src)[i];
  s4v o;
  o[0] = f2bf(v.x); o[1] = f2bf(v.y); o[2] = f2bf(v.z); o[3] = f2bf(v.w);
  reinterpret_cast<s4v*>(dst)[i] = o;
}

// ---------------- unified 8-phase GEMM (256x128 tile, BK=64) ----------------
// MODE 0: q = A @ Bt^T, epilogue scale+rope -> out0=q_full [B][H][S][192]
// MODE 1: kv = A @ Bt^T, epilogue -> out0=k_full, out1=v^T [B][H][128][S]
template<int K, int MODE>
__global__ __launch_bounds__(512, 2) void gemm8p_kernel(
    const short* __restrict__ A, const short* __restrict__ Bt,
    const float* __restrict__ cosb, const float* __restrict__ sinb,
    short* __restrict__ out0, short* __restrict__ out1,
    int gridN, int cpx) {
  constexpr int NT = K / 64;           // K-tiles
  __shared__ short sA[3][256 * 64];    // 3 x 32 KiB
  __shared__ short sB[3][128 * 64];    // 3 x 16 KiB
  const int id = blockIdx.x;
  const int swz = (id & 7) * cpx + (id >> 3);   // bijective (nwg%8==0)
  const int m0 = (swz / gridN) * 256;
  const int n0 = (swz % gridN) * 128;
  const int tid = threadIdx.x;
  const int w = tid >> 6, l = tid & 63;
  const int l15 = l & 15, lg = l >> 4;
  const int wm = w >> 1, wn = w & 1;   // 4M x 2N wave grid, 64x64 per wave
  const int rs7 = l15 & 7;

  // staging descriptors: thread covers rows r0, r0+8 of each 128-row unit,
  // phys slot l&7; LDS linear, source pre-swizzled (lslot = pslot ^ (row&7)).
  const int r0 = w * 16 + (l >> 3);
  const int lslot = (l & 7) ^ ((l >> 3) & 7);
  const char* pA[2][2]; const char* pB[2];
#pragma unroll
  for (int j = 0; j < 2; ++j) {
    const int rj = r0 + j * 8;
    pA[0][j] = (const char*)A + ((size_t)(m0 + rj) * K + lslot * 8) * 2;
    pA[1][j] = (const char*)A + ((size_t)(m0 + 128 + rj) * K + lslot * 8) * 2;
    pB[j]    = (const char*)Bt + ((size_t)(n0 + rj) * K + lslot * 8) * 2;
  }
  const int dst0 = (w * 2) * 1024, dst1 = (w * 2 + 1) * 1024;

  // prologue: stage tiles 0,1 into bufs 0,1 (6 loads/thread each)
#pragma unroll
  for (int t = 0; t < 2; ++t) {
    const int ko = t * 128;
    gll16(pA[0][0] + ko, (char*)sA[t] + dst0);
    gll16(pA[0][1] + ko, (char*)sA[t] + dst1);
    gll16(pA[1][0] + ko, (char*)sA[t] + 16384 + dst0);
    gll16(pA[1][1] + ko, (char*)sA[t] + 16384 + dst1);
    gll16(pB[0] + ko, (char*)sB[t] + dst0);
    gll16(pB[1] + ko, (char*)sB[t] + dst1);
  }
  asm volatile("s_waitcnt vmcnt(6)" ::: "memory");  // tile 0 landed
  __builtin_amdgcn_s_barrier();

  f4v acc[4][4] = {};
  s8v bf[4][2];
  int cur = 0;
  for (int t = 0; t < NT; ++t) {
    const char* bufA = (const char*)sA[cur];
    const char* bufB = (const char*)sB[cur];
    const int st = (cur >= 1) ? cur - 1 : cur + 2;  // (cur+2)%3
    const int ko = (t + 2) * 128;
    const bool stg = (t + 2 < NT);
    // ---- phase 1: 12 ds_reads (4A + 8B) + stage A-unit0 of tile t+2 ----
    s8v af[2][2];
#pragma unroll
    for (int kc = 0; kc < 2; ++kc) {
#pragma unroll
      for (int im = 0; im < 2; ++im) {
        const int ra = wm * 64 + im * 16 + l15;
        af[im][kc] = *(const s8v*)(bufA + ra * 128 + (((kc * 4 + lg) ^ rs7) << 4));
      }
#pragma unroll
      for (int nf = 0; nf < 4; ++nf) {
        const int rb = wn * 64 + nf * 16 + l15;
        bf[nf][kc] = *(const s8v*)(bufB + rb * 128 + (((kc * 4 + lg) ^ rs7) << 4));
      }
    }
    if (stg) {
      gll16(pA[0][0] + ko, (char*)sA[st] + dst0);
      gll16(pA[0][1] + ko, (char*)sA[st] + dst1);
    }
    __builtin_amdgcn_s_barrier();
    asm volatile("s_waitcnt lgkmcnt(0)" ::: "memory");
    __builtin_amdgcn_sched_barrier(0);
    __builtin_amdgcn_s_setprio(1);
#pragma unroll
    for (int im = 0; im < 2; ++im)
#pragma unroll
      for (int nf = 0; nf < 4; ++nf)
#pragma unroll
        for (int kc = 0; kc < 2; ++kc)
          acc[im][nf] = __builtin_amdgcn_mfma_f32_16x16x32_bf16(af[im][kc], bf[nf][kc], acc[im][nf], 0, 0, 0);
    __builtin_amdgcn_s_setprio(0);
    __builtin_amdgcn_s_barrier();
    // ---- phase 2: 4 ds_reads (A) + stage A-unit1 + B-unit of tile t+2 ----
#pragma unroll
    for (int kc = 0; kc < 2; ++kc)
#pragma unroll
      for (int im = 0; im < 2; ++im) {
        const int ra = wm * 64 + (2 + im) * 16 + l15;
        af[im][kc] = *(const s8v*)(bufA + ra * 128 + (((kc * 4 + lg) ^ rs7) << 4));
      }
    if (stg) {
      gll16(pA[1][0] + ko, (char*)sA[st] + 16384 + dst0);
      gll16(pA[1][1] + ko, (char*)sA[st] + 16384 + dst1);
      gll16(pB[0] + ko, (char*)sB[st] + dst0);
      gll16(pB[1] + ko, (char*)sB[st] + dst1);
    }
    __builtin_amdgcn_s_barrier();
    asm volatile("s_waitcnt lgkmcnt(0)" ::: "memory");
    __builtin_amdgcn_sched_barrier(0);
    __builtin_amdgcn_s_setprio(1);
#pragma unroll
    for (int im = 0; im < 2; ++im)
#pragma unroll
      for (int nf = 0; nf < 4; ++nf)
#pragma unroll
        for (int kc = 0; kc < 2; ++kc)
          acc[2 + im][nf] = __builtin_amdgcn_mfma_f32_16x16x32_bf16(af[im][kc], bf[nf][kc], acc[2 + im][nf], 0, 0, 0);
    __builtin_amdgcn_s_setprio(0);
    // boundary: ensure tile t+1 fully landed; keep tile t+2's 6 in flight
    if (stg) asm volatile("s_waitcnt vmcnt(6)" ::: "memory");
    else     asm volatile("s_waitcnt vmcnt(0)" ::: "memory");
    __builtin_amdgcn_s_barrier();
    cur = (cur == 2) ? 0 : cur + 1;
  }

  // epilogue: C/D layout col=l15 (n), row=lg*4+r (m)
#pragma unroll
  for (int j = 0; j < 4; ++j) {
    const int colb = n0 + wn * 64 + j * 16;
    if (MODE == 0) {
      const int e0 = colb % 192;       // 192=12*16: frag never crosses a head
      const int h = colb / 192;
      const int e = e0 + l15;
      const bool is_pe = (e0 >= 128);
#pragma unroll
      for (int i = 0; i < 4; ++i) {
#pragma unroll
        for (int r = 0; r < 4; ++r) {
          const int row = m0 + wm * 64 + i * 16 + lg * 4 + r;  // b*1024+s
          const int b = row >> 10, s = row & 1023;
          const size_t base = ((size_t)(b * H_ + h) * S_ + s) * 192;
          float val = acc[i][j][r] * SCALE_;
          if (!is_pe) {
            out0[base + e] = f2bf(val);
          } else {
            float other = __shfl_xor(val, 1, 64);
            int p = (e - 128) >> 1;
            float cv = cosb[(size_t)row * 64 + p];
            float sv = sinb[(size_t)row * 64 + p];
            float o = ((l & 1) == 0) ? (val * cv - other * sv) : (val * cv + other * sv);
            int ep = ((l & 1) == 0) ? (128 + p) : (160 + p);
            out0[base + ep] = f2bf(o);
          }
        }
      }
    } else {
      const int e0 = colb % 256;       // 256=16*16: frag never crosses a head
      const int h = colb / 256;
      const int e = e0 + l15;
      const bool is_v = (e0 >= 128);
#pragma unroll
      for (int i = 0; i < 4; ++i) {
#pragma unroll
        for (int r = 0; r < 4; ++r) {
          const int row = m0 + wm * 64 + i * 16 + lg * 4 + r;
          const int b = row >> 10, s = row & 1023;
          float val = acc[i][j][r];
          if (!is_v) {
            out0[((size_t)(b * H_ + h) * S_ + s) * 192 + e] = f2bf(val);
          } else {
            out1[((size_t)(b * H_ + h) * 128 + (e - 128)) * S_ + s] = f2bf(val);
          }
        }
      }
    }
  }
}

// ---------------- k_pe: rope(PE) broadcast to all heads ----------------
__global__ __launch_bounds__(64) void kpe_kernel(const float* __restrict__ PE,
                                                 const float* __restrict__ cosb,
                                                 const float* __restrict__ sinb,
                                                 short* __restrict__ kfull) {
  const int pos = blockIdx.x;           // 0..4095
  const int t = threadIdx.x;            // 0..63
  const int p = t & 31;
  float x0 = PE[(size_t)pos * 64 + 2 * p];
  float x1 = PE[(size_t)pos * 64 + 2 * p + 1];
  float cv = cosb[(size_t)pos * 64 + p];
  float sv = sinb[(size_t)pos * 64 + p];
  float o = (t < 32) ? (x0 * cv - x1 * sv) : (x1 * cv + x0 * sv);
  short ob = f2bf(o);
  const int b = pos >> 10, s = pos & 1023;
#pragma unroll
  for (int h = 0; h < H_; ++h)
    kfull[(((size_t)b * H_ + h) * S_ + s) * 192 + 128 + t] = ob;
}

// ---------------- causal flash attention (v2, unchanged) ----------------
// q_full/k_full: [B*H][S][192] bf16 (q pre-scaled); vt: [B*H][128][S] bf16
// out: [B][S][H][128] f32. Block = 128 q rows (4 waves x 32), KV tile = 64.
// Swapped QK^T: S^T = mfma(K, Q): lane holds P[q=l&15][kv=k0+T*16+lg*4+r].
// Swapped PV:   O^T = mfma(V^T, P^T): acc D[col=l15=q][row=lg*4+r=d].
__global__ __launch_bounds__(256, 2) void attn_kernel(
    const short* __restrict__ qfull, const short* __restrict__ kfull,
    const short* __restrict__ vt, float* __restrict__ out) {
  __shared__ short sK[2][64 * 192];     // double-buffered K tile, 48 KiB
  const int bid = blockIdx.x;
  const int qb = 7 - (bid >> 7);        // longest blocks first
  const int bh = bid & 127;
  const int b = bh >> 5, h = bh & 31;
  const int tid = threadIdx.x;
  const int w = tid >> 6, l = tid & 63;
  const int l15 = l & 15, lg = l >> 4;
  const short* Qh = qfull + (size_t)bh * (S_ * 192);
  const char*  KhB = (const char*)(kfull + (size_t)bh * (S_ * 192));
  const short* Vh = vt + (size_t)bh * (128 * S_);
  const int qw = qb * 128 + w * 32;     // this wave's q base (32 rows)

  // Q fragments (B-operand: lane l15 = q col, k = kc*32+lg*8..+7)
  s8v qfr[2][6];
#pragma unroll
  for (int mq = 0; mq < 2; ++mq)
#pragma unroll
    for (int kc = 0; kc < 6; ++kc)
      qfr[mq][kc] = *reinterpret_cast<const s8v*>(
          &Qh[(size_t)(qw + mq * 16 + l15) * 192 + kc * 32 + lg * 8]);

  // K staging offsets: LDS linear; source pre-swizzled (c ^ ((row&7)<<4)) so
  // readers at row*384 + (cw ^ swz) get K[row][cw] conflict-free.
  unsigned kOff[6];
#pragma unroll
  for (int c = 0; c < 6; ++c) {
    unsigned o = (unsigned)(w * 6 + c) * 1024u + (unsigned)l * 16u;
    unsigned row = o / 384u;
    unsigned cb = o - row * 384u;
    kOff[c] = row * 384u + (cb ^ ((row & 7u) << 4));
  }

  // prologue: stage tile 0 into buf 0
#pragma unroll
  for (int c = 0; c < 6; ++c)
    gll16(KhB + kOff[c], (char*)(&sK[0][0]) + (w * 6 + c) * 1024);
  __syncthreads();

  f4v acc[8][2] = {};
  float mrun[2] = {-3.0e38f, -3.0e38f};
  float lsum[2] = {0.f, 0.f};
  const int nt = 2 * (qb + 1);
  int cur = 0;
  for (int t = 0; t < nt; ++t) {
    const int k0 = t * 64;
    if (t + 1 < nt) {                   // prefetch next tile into other buffer
      const char* gb = KhB + (size_t)(t + 1) * (64 * 384);
      char* lb = (char*)(&sK[cur ^ 1][0]);
#pragma unroll
      for (int c = 0; c < 6; ++c)
        gll16(gb + kOff[c], lb + (w * 6 + c) * 1024);
    }
    if (k0 <= qw + 31) {                // wave-uniform causal skip
      const char* sKc = (const char*)(&sK[cur][0]);
      f4v s[4][2] = {};
#pragma unroll
      for (int T = 0; T < 4; ++T) {
        const int row = T * 16 + l15;
        const unsigned swz = (unsigned)((row & 7) << 4);
#pragma unroll
        for (int kc = 0; kc < 6; ++kc) {
          s8v kf = *reinterpret_cast<const s8v*>(
              sKc + row * 384 + (unsigned)((kc * 64 + lg * 16) ^ swz));
          s[T][0] = __builtin_amdgcn_mfma_f32_16x16x32_bf16(kf, qfr[0][kc], s[T][0], 0, 0, 0);
          s[T][1] = __builtin_amdgcn_mfma_f32_16x16x32_bf16(kf, qfr[1][kc], s[T][1], 0, 0, 0);
        }
      }
      const bool diag = (t >= 2 * qb);
      unsigned pk[4][2][2];
#pragma unroll
      for (int mq = 0; mq < 2; ++mq) {
        const int qlane = qw + mq * 16 + l15;
        if (diag) {
#pragma unroll
          for (int T = 0; T < 4; ++T)
#pragma unroll
            for (int r = 0; r < 4; ++r)
              if (k0 + T * 16 + lg * 4 + r > qlane) s[T][mq][r] = -1.0e30f;
        }
        float tmax = s[0][mq][0];
#pragma unroll
        for (int T = 0; T < 4; ++T)
#pragma unroll
          for (int r = 0; r < 4; ++r) tmax = fmaxf(tmax, s[T][mq][r]);
        tmax = fmaxf(tmax, __shfl_xor(tmax, 16, 64));
        tmax = fmaxf(tmax, __shfl_xor(tmax, 32, 64));
        const float mnew = fmaxf(mrun[mq], tmax);
        const float cf = __expf(mrun[mq] - mnew);
        mrun[mq] = mnew;
        float rs = 0.f;
#pragma unroll
        for (int T = 0; T < 4; ++T)
#pragma unroll
          for (int r = 0; r < 4; ++r) {
            float e = __expf(s[T][mq][r] - mnew);
            s[T][mq][r] = e;
            rs += e;
          }
        rs += __shfl_xor(rs, 16, 64);
        rs += __shfl_xor(rs, 32, 64);
        lsum[mq] = lsum[mq] * cf + rs;
#pragma unroll
        for (int dt = 0; dt < 8; ++dt)
#pragma unroll
          for (int r = 0; r < 4; ++r) acc[dt][mq][r] *= cf;
#pragma unroll
        for (int T = 0; T < 4; ++T) {
          pk[T][mq][0] = (unsigned)(unsigned short)f2bf(s[T][mq][0]) |
                         ((unsigned)(unsigned short)f2bf(s[T][mq][1]) << 16);
          pk[T][mq][1] = (unsigned)(unsigned short)f2bf(s[T][mq][2]) |
                         ((unsigned)(unsigned short)f2bf(s[T][mq][3]) << 16);
        }
      }
      // PV: B-frag word j2 of chunk c2 = pk[2c2+(lg>>1)][j2&1] from lane
      // l15 + 16*((lg&1)*2 + (j2>>1))  (derived + verified lane mapping)
#pragma unroll
      for (int c2 = 0; c2 < 2; ++c2) {
        union { unsigned u[4]; s8v v; } bb[2];
#pragma unroll
        for (int mq = 0; mq < 2; ++mq)
#pragma unroll
          for (int j2 = 0; j2 < 4; ++j2) {
            int src = l15 + ((l & 16) << 1) + ((j2 & 2) << 3);
            unsigned va = (unsigned)__shfl((int)pk[2 * c2][mq][j2 & 1], src, 64);
            unsigned vb = (unsigned)__shfl((int)pk[2 * c2 + 1][mq][j2 & 1], src, 64);
            bb[mq].u[j2] = (l & 32) ? vb : va;
          }
#pragma unroll
        for (int dt = 0; dt < 8; ++dt) {
          s8v vf = *reinterpret_cast<const s8v*>(
              &Vh[(size_t)(dt * 16 + l15) * S_ + k0 + c2 * 32 + lg * 8]);
          acc[dt][0] = __builtin_amdgcn_mfma_f32_16x16x32_bf16(vf, bb[0].v, acc[dt][0], 0, 0, 0);
          acc[dt][1] = __builtin_amdgcn_mfma_f32_16x16x32_bf16(vf, bb[1].v, acc[dt][1], 0, 0, 0);
        }
      }
    }
    __syncthreads();                    // drains prefetch (vmcnt0) + LDS reads
    cur ^= 1;
  }
  // epilogue: O[q][d], 64B-coalesced float4 stores
#pragma unroll
  for (int mq = 0; mq < 2; ++mq) {
    const float inv = 1.0f / lsum[mq];
    const int q = qw + mq * 16 + l15;
    float* ob = out + (((size_t)b * S_ + q) * H_ + h) * 128 + lg * 4;
#pragma unroll
    for (int dt = 0; dt < 8; ++dt) {
      float4 o4 = { acc[dt][mq][0] * inv, acc[dt][mq][1] * inv,
                    acc[dt][mq][2] * inv, acc[dt][mq][3] * inv };
      *reinterpret_cast<float4*>(ob + dt * 16) = o4;
    }
  }
}

// ---------------- launch ----------------
extern "C" void kernel_launch(void* const* d_in, const int* in_sizes, int n_in,
                              void* d_out, int out_size, void* d_ws, size_t ws_size,
                              hipStream_t stream) {
  const float* Q    = (const float*)d_in[0];
  const float* KV   = (const float*)d_in[1];
  const float* PE   = (const float*)d_in[2];
  const float* WUQ  = (const float*)d_in[3];
  const float* WUKV = (const float*)d_in[4];
  const float* cosb = (const float*)d_in[5];
  const float* sinb = (const float*)d_in[6];
  float* out = (float*)d_out;
  char* ws = (char*)d_ws;

  short* Qb    = (short*)(ws);                   // 4096*1536*2  = 12,582,912
  short* Wq    = (short*)(ws + 12582912);        // 6144*1536*2  = 18,874,368
  short* KVb   = (short*)(ws + 31457280);        // 4096*512*2   =  4,194,304
  short* Wkv   = (short*)(ws + 35651584);        // 8192*512*2   =  8,388,608
  short* qfull = (short*)(ws + 44040192);        // 4*32*1024*192*2 = 50,331,648
  short* kfull = (short*)(ws + 94371840);        // 50,331,648
  short* vtb   = (short*)(ws + 144703488);       // 4*32*128*1024*2 = 33,554,432

  convert_f32_bf16<<<6144, 256, 0, stream>>>(Q, Qb, 1572864);
  convert_f32_bf16<<<9216, 256, 0, stream>>>(WUQ, Wq, 2359296);
  convert_f32_bf16<<<2048, 256, 0, stream>>>(KV, KVb, 524288);
  convert_f32_bf16<<<4096, 256, 0, stream>>>(WUKV, Wkv, 1048576);

  // gemm_q: M=4096 N=6144 -> grid 16x48=768 (cpx=96)
  gemm8p_kernel<1536, 0><<<768, 512, 0, stream>>>(Qb, Wq, cosb, sinb, qfull, nullptr, 48, 96);
  // gemm_kv: M=4096 N=8192 -> grid 16x64=1024 (cpx=128)
  gemm8p_kernel<512, 1><<<1024, 512, 0, stream>>>(KVb, Wkv, nullptr, nullptr, kfull, vtb, 64, 128);
  kpe_kernel<<<4096, 64, 0, stream>>>(PE, cosb, sinb, kfull);

  attn_kernel<<<1024, 256, 0, stream>>>(qfull, kfull, vtb, out);
}